// Round 2
// 506.879 us; speedup vs baseline: 1.1250x; 1.1250x over previous
//
#include <hip/hip_runtime.h>
#include <cstdint>
#include <cstddef>

// Out[M][N] = X[M][K] @ W[N][K]^T + bias[N].  f32 storage, bf16 MFMA compute.
#define M_DIM 8192
#define N_DIM 4096
#define K_DIM 4096

typedef __bf16 bf16x8 __attribute__((ext_vector_type(8)));
typedef float  f32x4  __attribute__((ext_vector_type(4)));
typedef unsigned short u16x4 __attribute__((ext_vector_type(4)));
typedef unsigned short u16x8 __attribute__((ext_vector_type(8)));

__device__ __forceinline__ unsigned short f32_to_bf16(float f) {
    unsigned int v = __builtin_bit_cast(unsigned int, f);
    v += 0x7FFFu + ((v >> 16) & 1u);   // round-to-nearest-even
    return (unsigned short)(v >> 16);
}

__device__ __forceinline__ void load16_lds(const void* g, void* l) {
    __builtin_amdgcn_global_load_lds(
        (__attribute__((address_space(1))) void*)(g),
        (__attribute__((address_space(3))) void*)(l),
        16, 0, 0);
}

// Counted waits + barrier. ALL carry "memory" clobbers so no memory op
// (ds_read or global_load_lds) can be compiler-moved across them — bare
// __builtin_amdgcn_s_barrier() is NOT a compiler fence and allows a
// cross-wave stale-read race on the LDS ring.
#define VMCNT(n) asm volatile("s_waitcnt vmcnt(" #n ")" ::: "memory")
#define LGKM0()  asm volatile("s_waitcnt lgkmcnt(0)" ::: "memory")
#define BAR()    asm volatile("s_barrier" ::: "memory")

// ---------- pre-pass: f32 -> bf16 (RNE), both tensors in one launch ----------
__global__ void cvt_f32_to_bf16_2(const float* __restrict__ X,
                                  const float* __restrict__ W,
                                  unsigned short* __restrict__ dX,
                                  unsigned short* __restrict__ dW,
                                  int nX8, int nTot8) {
    int i = blockIdx.x * blockDim.x + threadIdx.x;
    const int stride = gridDim.x * blockDim.x;
    for (; i < nTot8; i += stride) {
        const float* s; unsigned short* d; int k;
        if (i < nX8) { s = X; d = dX; k = i; }
        else         { s = W; d = dW; k = i - nX8; }
        f32x4 a = *(const f32x4*)(s + (size_t)k * 8);
        f32x4 b = *(const f32x4*)(s + (size_t)k * 8 + 4);
        u16x8 o;
        o[0] = f32_to_bf16(a.x); o[1] = f32_to_bf16(a.y);
        o[2] = f32_to_bf16(a.z); o[3] = f32_to_bf16(a.w);
        o[4] = f32_to_bf16(b.x); o[5] = f32_to_bf16(b.y);
        o[6] = f32_to_bf16(b.z); o[7] = f32_to_bf16(b.w);
        *(u16x8*)(d + (size_t)k * 8) = o;
    }
}

// ---------- main GEMM: 256x256 tile, BK=32 slices, 4-deep LDS ring ----------
// 512 threads = 8 waves (2M x 4N), per-wave 128x64 output (8x4 16x16 frags).
// LDS: 4 buffers x (A 256x32 + B 256x32) bf16 = 128 KiB (1 block/CU).
// Per slice t: [ds_read frags -> 32 MFMA (setprio)] ; lgkmcnt(0);
// vmcnt(8) (retire slice t+1, keep t+2,t+3 in flight); s_barrier; stage t+4.
// One barrier per BK=32; vmcnt never drains to 0 in the main loop (T3/T4).
// T2: 16B-chunk XOR swizzle (pos ^= (row>>1)&3) applied on the pre-swizzled
// global source at stage time and on the ds_read address (both-sides, rule 21).
__global__ __launch_bounds__(512, 2) void gemm_256_pipe(
    const unsigned short* __restrict__ X,    // [M][K] bf16 (ws)
    const unsigned short* __restrict__ W,    // [N][K] bf16 (ws)
    const float* __restrict__ Bias,          // [N] f32
    float* __restrict__ Out)                 // [M][N] f32
{
    __shared__ alignas(16) unsigned short ldsA[4][8192];   // [buf][256*32]
    __shared__ alignas(16) unsigned short ldsB[4][8192];

    const int tid  = threadIdx.x;
    const int wave = tid >> 6;
    const int lane = tid & 63;

    // T1: XCD-aware bijective swizzle. 512 wgs, 8 XCDs, 64 wgs/XCD chunk.
    const int bid = blockIdx.x;
    const int wg  = (bid & 7) * 64 + (bid >> 3);
    const int tileM = (wg >> 4) * 256;     // 32 tile-rows
    const int tileN = (wg & 15) * 256;     // 16 tile-cols

    // ---- staging addresses (per-thread, pre-swizzled global source) ----
    // LDS byte of an 8KB issue: row = tid/4, phys 16B pos = tid&3.
    // Logical chunk placed there = phys ^ ((row>>1)&3)  [(tid>>3)&3].
    const int row4 = tid >> 2;                                  // 0..127
    const int swzc = (((tid & 3) ^ ((tid >> 3) & 3)) << 3);     // elems
    const unsigned short* gA0 = X + (size_t)(tileM + row4) * K_DIM + swzc;
    const unsigned short* gA1 = gA0 + (size_t)128 * K_DIM;
    const unsigned short* gB0 = W + (size_t)(tileN + row4) * K_DIM + swzc;
    const unsigned short* gB1 = gB0 + (size_t)128 * K_DIM;

    // ---- fragment read bases ----
    const int fr = lane & 15;   // row within 16-block (A: m, B: n)
    const int fq = lane >> 4;   // logical k-chunk (8 bf16)
    const int wm = wave >> 2;   // 0..1
    const int wn = wave & 3;    // 0..3
    // phys chunk = fq ^ ((row>>1)&3); row = (mult of 16) + fr -> per-lane const.
    const int kpos = ((fq ^ ((fr >> 1) & 3)) << 3);             // elems
    const unsigned short* aBase = &ldsA[0][(wm * 128 + fr) * 32 + kpos];
    const unsigned short* bBase = &ldsB[0][(wn * 64  + fr) * 32 + kpos];

    f32x4 acc[8][4];
    #pragma unroll
    for (int i = 0; i < 8; ++i)
        #pragma unroll
        for (int j = 0; j < 4; ++j)
            acc[i][j] = f32x4{0.f, 0.f, 0.f, 0.f};

#define STAGE(s, b) do {                                        \
        const int ko_ = (s) * 32;                               \
        load16_lds(gA0 + ko_, &ldsA[b][       wave * 512]);     \
        load16_lds(gA1 + ko_, &ldsA[b][4096 + wave * 512]);     \
        load16_lds(gB0 + ko_, &ldsB[b][       wave * 512]);     \
        load16_lds(gB1 + ko_, &ldsB[b][4096 + wave * 512]);     \
    } while (0)

#define SLICE(b) do {                                           \
        const unsigned short* pa_ = aBase + (b) * 8192;         \
        const unsigned short* pb_ = bBase + (b) * 8192;         \
        bf16x8 af[8]; bf16x8 bv[4];                             \
        _Pragma("unroll")                                       \
        for (int i = 0; i < 8; ++i)                             \
            af[i] = *(const bf16x8*)(pa_ + i * 512);            \
        _Pragma("unroll")                                       \
        for (int j = 0; j < 4; ++j)                             \
            bv[j] = *(const bf16x8*)(pb_ + j * 512);            \
        __builtin_amdgcn_s_setprio(1);                          \
        _Pragma("unroll")                                       \
        for (int i = 0; i < 8; ++i)                             \
            _Pragma("unroll")                                   \
            for (int j = 0; j < 4; ++j)                         \
                acc[i][j] = __builtin_amdgcn_mfma_f32_16x16x32_bf16( \
                    af[i], bv[j], acc[i][j], 0, 0, 0);          \
        __builtin_amdgcn_s_setprio(0);                          \
    } while (0)

    // ---- prologue: fill the 4-deep ring, retire slice 0 only ----
    STAGE(0, 0); STAGE(1, 1); STAGE(2, 2); STAGE(3, 3);
    VMCNT(12);          // <=12 outstanding -> slice 0 (own 4 loads) landed
    BAR();              // all waves' slice-0 loads landed

    // ---- main loop: slices 0..123, stage t+4, never drain vmcnt ----
    #pragma unroll 1
    for (int t4 = 0; t4 < 124; t4 += 4) {
        SLICE(0); LGKM0(); VMCNT(8); BAR(); STAGE(t4 + 4, 0);
        SLICE(1); LGKM0(); VMCNT(8); BAR(); STAGE(t4 + 5, 1);
        SLICE(2); LGKM0(); VMCNT(8); BAR(); STAGE(t4 + 6, 2);
        SLICE(3); LGKM0(); VMCNT(8); BAR(); STAGE(t4 + 7, 3);
    }
    // ---- epilogue: slices 124..127, draining counts 8 -> 4 -> 0 ----
    SLICE(0); LGKM0(); VMCNT(8); BAR();   // t=124: retire 125 (126,127 fly)
    SLICE(1); LGKM0(); VMCNT(4); BAR();   // t=125: retire 126
    SLICE(2); LGKM0(); VMCNT(0); BAR();   // t=126: retire 127
    SLICE(3);                              // t=127

#undef STAGE
#undef SLICE

    // ---- C write + bias ----
    #pragma unroll
    for (int j = 0; j < 4; ++j) {
        const int col = tileN + wn * 64 + j * 16 + fr;
        const float bvl = Bias[col];
        #pragma unroll
        for (int i = 0; i < 8; ++i) {
            const int rowb = tileM + wm * 128 + i * 16 + fq * 4;
            f32x4 v = acc[i][j];
            #pragma unroll
            for (int r = 0; r < 4; ++r)
                Out[(size_t)(rowb + r) * N_DIM + col] = v[r] + bvl;
        }
    }
}

// ---------- fallback GEMM (ws too small): f32 load + cvt during staging ----
__global__ __launch_bounds__(256, 3) void gemm_bt_reg(
    const float* __restrict__ X,    // [M][K] f32
    const float* __restrict__ W,    // [N][K] f32
    const float* __restrict__ Bias,
    float* __restrict__ Out)
{
    __shared__ alignas(16) unsigned short sA[2][128][32];
    __shared__ alignas(16) unsigned short sB[2][128][32];

    const int tid  = threadIdx.x;
    const int wave = tid >> 6;
    const int lane = tid & 63;
    const int tileM = blockIdx.x * 128;
    const int tileN = blockIdx.y * 128;

    const int fr = lane & 15;
    const int fq = lane >> 4;
    const int wm = (wave >> 1) * 64;
    const int wn = (wave & 1) * 64;

    f32x4 acc[4][4];
    #pragma unroll
    for (int i = 0; i < 4; ++i)
        #pragma unroll
        for (int j = 0; j < 4; ++j)
            acc[i][j] = f32x4{0.f, 0.f, 0.f, 0.f};

    for (int k0 = 0; k0 < K_DIM; k0 += 64) {
        __syncthreads();
        #pragma unroll
        for (int ks = 0; ks < 2; ++ks) {
            #pragma unroll
            for (int jj = 0; jj < 4; ++jj) {
                const int f   = tid + jj * 256;   // 0..1023
                const int row = f >> 3;
                const int c4  = (f & 7) * 4;
                f32x4 va = *(const f32x4*)(X + (size_t)(tileM + row) * K_DIM + k0 + ks * 32 + c4);
                f32x4 vb = *(const f32x4*)(W + (size_t)(tileN + row) * K_DIM + k0 + ks * 32 + c4);
                u16x4 oa, ob;
                oa.x = f32_to_bf16(va.x); oa.y = f32_to_bf16(va.y);
                oa.z = f32_to_bf16(va.z); oa.w = f32_to_bf16(va.w);
                ob.x = f32_to_bf16(vb.x); ob.y = f32_to_bf16(vb.y);
                ob.z = f32_to_bf16(vb.z); ob.w = f32_to_bf16(vb.w);
                *(u16x4*)&sA[ks][row][c4] = oa;
                *(u16x4*)&sB[ks][row][c4] = ob;
            }
        }
        __syncthreads();

        #pragma unroll
        for (int ks = 0; ks < 2; ++ks) {
            bf16x8 af[4], bfr[4];
            #pragma unroll
            for (int i = 0; i < 4; ++i) {
                af[i]  = *(const bf16x8*)&sA[ks][wm + i * 16 + fr][fq * 8];
                bfr[i] = *(const bf16x8*)&sB[ks][wn + i * 16 + fr][fq * 8];
            }
            #pragma unroll
            for (int i = 0; i < 4; ++i)
                #pragma unroll
                for (int j = 0; j < 4; ++j)
                    acc[i][j] = __builtin_amdgcn_mfma_f32_16x16x32_bf16(
                        af[i], bfr[j], acc[i][j], 0, 0, 0);
        }
    }

    #pragma unroll
    for (int j = 0; j < 4; ++j) {
        const int col = tileN + wn + j * 16 + fr;
        const float bv = Bias[col];
        #pragma unroll
        for (int i = 0; i < 4; ++i) {
            const int rowb = tileM + wm + i * 16 + fq * 4;
            f32x4 v = acc[i][j];
            #pragma unroll
            for (int r = 0; r < 4; ++r)
                Out[(size_t)(rowb + r) * N_DIM + col] = v[r] + bv;
        }
    }
}

extern "C" void kernel_launch(void* const* d_in, const int* in_sizes, int n_in,
                              void* d_out, int out_size, void* d_ws, size_t ws_size,
                              hipStream_t stream) {
    const float* X    = (const float*)d_in[0];  // [8192][4096]
    const float* W    = (const float*)d_in[1];  // [4096][4096]
    const float* Bias = (const float*)d_in[2];  // [4096]
    float* Out = (float*)d_out;

    const size_t nX = (size_t)M_DIM * K_DIM;          // 33554432
    const size_t nW = (size_t)N_DIM * K_DIM;          // 16777216
    const size_t need = (nX + nW) * sizeof(unsigned short);  // ~96 MB

    if (ws_size >= need) {
        unsigned short* wsX = (unsigned short*)d_ws;
        unsigned short* wsW = wsX + nX;
        const int nX8   = (int)(nX / 8);
        const int nTot8 = (int)((nX + nW) / 8);
        cvt_f32_to_bf16_2<<<2048, 256, 0, stream>>>(X, W, wsX, wsW, nX8, nTot8);
        gemm_256_pipe<<<dim3(512), dim3(512), 0, stream>>>(wsX, wsW, Bias, Out);
    } else {
        dim3 grid(M_DIM / 128, N_DIM / 128);
        gemm_bt_reg<<<grid, dim3(256), 0, stream>>>(X, W, Bias, Out);
    }
}

// Round 3
// 490.988 us; speedup vs baseline: 1.1614x; 1.0324x over previous
//
#include <hip/hip_runtime.h>
#include <cstdint>
#include <cstddef>

// Out[M][N] = X[M][K] @ W[N][K]^T + bias[N].  f32 storage, bf16 MFMA compute.
#define M_DIM 8192
#define N_DIM 4096
#define K_DIM 4096

typedef __bf16 bf16x8 __attribute__((ext_vector_type(8)));
typedef float  f32x4  __attribute__((ext_vector_type(4)));
typedef unsigned short u16x4 __attribute__((ext_vector_type(4)));
typedef unsigned short u16x8 __attribute__((ext_vector_type(8)));

__device__ __forceinline__ unsigned short f32_to_bf16(float f) {
    unsigned int v = __builtin_bit_cast(unsigned int, f);
    v += 0x7FFFu + ((v >> 16) & 1u);   // round-to-nearest-even
    return (unsigned short)(v >> 16);
}

__device__ __forceinline__ void load16_lds(const void* g, void* l) {
    __builtin_amdgcn_global_load_lds(
        (__attribute__((address_space(1))) void*)(g),
        (__attribute__((address_space(3))) void*)(l),
        16, 0, 0);
}

// All carry "memory" clobbers: no memory op may be compiler-moved across.
#define VMCNT(n) asm volatile("s_waitcnt vmcnt(" #n ")" ::: "memory")
#define BAR()    asm volatile("s_barrier" ::: "memory")

// ---------- pre-pass: f32 -> bf16 (RNE), both tensors in one launch ----------
__global__ void cvt_f32_to_bf16_2(const float* __restrict__ X,
                                  const float* __restrict__ W,
                                  unsigned short* __restrict__ dX,
                                  unsigned short* __restrict__ dW,
                                  int nX8, int nTot8) {
    int i = blockIdx.x * blockDim.x + threadIdx.x;
    const int stride = gridDim.x * blockDim.x;
    for (; i < nTot8; i += stride) {
        const float* s; unsigned short* d; int k;
        if (i < nX8) { s = X; d = dX; k = i; }
        else         { s = W; d = dW; k = i - nX8; }
        f32x4 a = *(const f32x4*)(s + (size_t)k * 8);
        f32x4 b = *(const f32x4*)(s + (size_t)k * 8 + 4);
        u16x8 o;
        o[0] = f32_to_bf16(a.x); o[1] = f32_to_bf16(a.y);
        o[2] = f32_to_bf16(a.z); o[3] = f32_to_bf16(a.w);
        o[4] = f32_to_bf16(b.x); o[5] = f32_to_bf16(b.y);
        o[6] = f32_to_bf16(b.z); o[7] = f32_to_bf16(b.w);
        *(u16x8*)(d + (size_t)k * 8) = o;
    }
}

// ---------- main GEMM: 256x256 tile, BK=32 slices, 4-deep LDS ring ----------
// 512 threads = 8 waves (2M x 4N), per-wave 128x64 output (8x4 16x16 frags).
// LDS: 4 buffers x (A 256x32 + B 256x32) bf16 = 128 KiB (1 block/CU).
// m201-style latency hiding with NO extra VGPRs: per slice t,
//   R(t): 12 ds_read from buf[t&3]           (issue only)
//   VMCNT(4); BAR(); STAGE(t+3); sched_barrier(0);
//   setprio(1); 32 MFMA; setprio(0)
// The ~120cy LDS latency is absorbed by the vmcnt/bar/stage window instead of
// sitting serially ahead of the MFMA cluster (the R2 46%-MfmaUtil failure).
// Invariants (vmcnt counts stage loads, 4/slice):
//   at slice t's VMCNT(4): outstanding = stages {t+1,t+2} -> retire t+1.
//   buf[(t+3)&3] overwrite hits slice t-1's data; its reads were consumed by
//   MFMA(t-1) before this slice's BAR -> race-free.
// T2: 16B-chunk XOR swizzle (pos ^= (row>>1)&3) on pre-swizzled global source
// and on the ds_read address (both-sides, rule 21). Measured 0 conflicts.
__global__ __launch_bounds__(512, 2) void gemm_256_pipe(
    const unsigned short* __restrict__ X,    // [M][K] bf16 (ws)
    const unsigned short* __restrict__ W,    // [N][K] bf16 (ws)
    const float* __restrict__ Bias,          // [N] f32
    float* __restrict__ Out)                 // [M][N] f32
{
    __shared__ alignas(16) unsigned short ldsA[4][8192];   // [buf][256*32]
    __shared__ alignas(16) unsigned short ldsB[4][8192];

    const int tid  = threadIdx.x;
    const int wave = tid >> 6;
    const int lane = tid & 63;

    // T1: XCD-aware bijective swizzle. 512 wgs, 8 XCDs, 64 wgs/XCD chunk.
    const int bid = blockIdx.x;
    const int wg  = (bid & 7) * 64 + (bid >> 3);
    const int tileM = (wg >> 4) * 256;     // 32 tile-rows
    const int tileN = (wg & 15) * 256;     // 16 tile-cols

    // ---- staging addresses (per-thread, pre-swizzled global source) ----
    const int row4 = tid >> 2;                                  // 0..127
    const int swzc = (((tid & 3) ^ ((tid >> 3) & 3)) << 3);     // elems
    const unsigned short* gA0 = X + (size_t)(tileM + row4) * K_DIM + swzc;
    const unsigned short* gA1 = gA0 + (size_t)128 * K_DIM;
    const unsigned short* gB0 = W + (size_t)(tileN + row4) * K_DIM + swzc;
    const unsigned short* gB1 = gB0 + (size_t)128 * K_DIM;

    // ---- fragment read bases ----
    const int fr = lane & 15;   // row within 16-block (A: m, B: n)
    const int fq = lane >> 4;   // logical k-chunk (8 bf16)
    const int wm = wave >> 2;   // 0..1
    const int wn = wave & 3;    // 0..3
    const int kpos = ((fq ^ ((fr >> 1) & 3)) << 3);             // elems
    const unsigned short* aBase = &ldsA[0][(wm * 128 + fr) * 32 + kpos];
    const unsigned short* bBase = &ldsB[0][(wn * 64  + fr) * 32 + kpos];

    f32x4 acc[8][4];
    #pragma unroll
    for (int i = 0; i < 8; ++i)
        #pragma unroll
        for (int j = 0; j < 4; ++j)
            acc[i][j] = f32x4{0.f, 0.f, 0.f, 0.f};

#define STAGE(s, b) do {                                        \
        const int ko_ = (s) * 32;                               \
        load16_lds(gA0 + ko_, &ldsA[b][       wave * 512]);     \
        load16_lds(gA1 + ko_, &ldsA[b][4096 + wave * 512]);     \
        load16_lds(gB0 + ko_, &ldsB[b][       wave * 512]);     \
        load16_lds(gB1 + ko_, &ldsB[b][4096 + wave * 512]);     \
    } while (0)

    // one pipelined slice: reads -> sync/stage window -> MFMA cluster
#define SLICE_PIPE(b, do_stage, ss, sb, vm) do {                \
        const unsigned short* pa_ = aBase + (b) * 8192;         \
        const unsigned short* pb_ = bBase + (b) * 8192;         \
        bf16x8 af[8]; bf16x8 bv[4];                             \
        _Pragma("unroll")                                       \
        for (int i = 0; i < 8; ++i)                             \
            af[i] = *(const bf16x8*)(pa_ + i * 512);            \
        _Pragma("unroll")                                       \
        for (int j = 0; j < 4; ++j)                             \
            bv[j] = *(const bf16x8*)(pb_ + j * 512);            \
        VMCNT(vm);                                              \
        BAR();                                                  \
        if (do_stage) STAGE(ss, sb);                            \
        __builtin_amdgcn_sched_barrier(0);                      \
        __builtin_amdgcn_s_setprio(1);                          \
        _Pragma("unroll")                                       \
        for (int i = 0; i < 8; ++i)                             \
            _Pragma("unroll")                                   \
            for (int j = 0; j < 4; ++j)                         \
                acc[i][j] = __builtin_amdgcn_mfma_f32_16x16x32_bf16( \
                    af[i], bv[j], acc[i][j], 0, 0, 0);          \
        __builtin_amdgcn_s_setprio(0);                          \
    } while (0)

    // ---- prologue: stage slices 0,1,2; retire slice 0 ----
    STAGE(0, 0); STAGE(1, 1); STAGE(2, 2);
    VMCNT(8);           // 12 outstanding -> retire slice 0
    BAR();

    // ---- main loop: slices 0..123 (stage t+3 = 3..126) ----
    #pragma unroll 1
    for (int t4 = 0; t4 < 124; t4 += 4) {
        SLICE_PIPE(0, true, t4 + 3, 3, 4);
        SLICE_PIPE(1, true, t4 + 4, 0, 4);
        SLICE_PIPE(2, true, t4 + 5, 1, 4);
        SLICE_PIPE(3, true, t4 + 6, 2, 4);
    }
    // ---- tail: slices 124..127 ----
    SLICE_PIPE(0, true, 127, 3, 4);   // t=124: retire 125, stage 127
    SLICE_PIPE(1, false, 0, 0, 4);    // t=125: retire 126 ({126,127} out)
    SLICE_PIPE(2, false, 0, 0, 0);    // t=126: retire 127
    SLICE_PIPE(3, false, 0, 0, 63);   // t=127: no wait needed (vmcnt 63 = nop)

#undef STAGE
#undef SLICE_PIPE

    // ---- C write + bias ----
    #pragma unroll
    for (int j = 0; j < 4; ++j) {
        const int col = tileN + wn * 64 + j * 16 + fr;
        const float bvl = Bias[col];
        #pragma unroll
        for (int i = 0; i < 8; ++i) {
            const int rowb = tileM + wm * 128 + i * 16 + fq * 4;
            f32x4 v = acc[i][j];
            #pragma unroll
            for (int r = 0; r < 4; ++r)
                Out[(size_t)(rowb + r) * N_DIM + col] = v[r] + bvl;
        }
    }
}

// ---------- fallback GEMM (ws too small): f32 load + cvt during staging ----
__global__ __launch_bounds__(256, 3) void gemm_bt_reg(
    const float* __restrict__ X,    // [M][K] f32
    const float* __restrict__ W,    // [N][K] f32
    const float* __restrict__ Bias,
    float* __restrict__ Out)
{
    __shared__ alignas(16) unsigned short sA[2][128][32];
    __shared__ alignas(16) unsigned short sB[2][128][32];

    const int tid  = threadIdx.x;
    const int wave = tid >> 6;
    const int lane = tid & 63;
    const int tileM = blockIdx.x * 128;
    const int tileN = blockIdx.y * 128;

    const int fr = lane & 15;
    const int fq = lane >> 4;
    const int wm = (wave >> 1) * 64;
    const int wn = (wave & 1) * 64;

    f32x4 acc[4][4];
    #pragma unroll
    for (int i = 0; i < 4; ++i)
        #pragma unroll
        for (int j = 0; j < 4; ++j)
            acc[i][j] = f32x4{0.f, 0.f, 0.f, 0.f};

    for (int k0 = 0; k0 < K_DIM; k0 += 64) {
        __syncthreads();
        #pragma unroll
        for (int ks = 0; ks < 2; ++ks) {
            #pragma unroll
            for (int jj = 0; jj < 4; ++jj) {
                const int f   = tid + jj * 256;   // 0..1023
                const int row = f >> 3;
                const int c4  = (f & 7) * 4;
                f32x4 va = *(const f32x4*)(X + (size_t)(tileM + row) * K_DIM + k0 + ks * 32 + c4);
                f32x4 vb = *(const f32x4*)(W + (size_t)(tileN + row) * K_DIM + k0 + ks * 32 + c4);
                u16x4 oa, ob;
                oa.x = f32_to_bf16(va.x); oa.y = f32_to_bf16(va.y);
                oa.z = f32_to_bf16(va.z); oa.w = f32_to_bf16(va.w);
                ob.x = f32_to_bf16(vb.x); ob.y = f32_to_bf16(vb.y);
                ob.z = f32_to_bf16(vb.z); ob.w = f32_to_bf16(vb.w);
                *(u16x4*)&sA[ks][row][c4] = oa;
                *(u16x4*)&sB[ks][row][c4] = ob;
            }
        }
        __syncthreads();

        #pragma unroll
        for (int ks = 0; ks < 2; ++ks) {
            bf16x8 af[4], bfr[4];
            #pragma unroll
            for (int i = 0; i < 4; ++i) {
                af[i]  = *(const bf16x8*)&sA[ks][wm + i * 16 + fr][fq * 8];
                bfr[i] = *(const bf16x8*)&sB[ks][wn + i * 16 + fr][fq * 8];
            }
            #pragma unroll
            for (int i = 0; i < 4; ++i)
                #pragma unroll
                for (int j = 0; j < 4; ++j)
                    acc[i][j] = __builtin_amdgcn_mfma_f32_16x16x32_bf16(
                        af[i], bfr[j], acc[i][j], 0, 0, 0);
        }
    }

    #pragma unroll
    for (int j = 0; j < 4; ++j) {
        const int col = tileN + wn + j * 16 + fr;
        const float bv = Bias[col];
        #pragma unroll
        for (int i = 0; i < 4; ++i) {
            const int rowb = tileM + wm + i * 16 + fq * 4;
            f32x4 v = acc[i][j];
            #pragma unroll
            for (int r = 0; r < 4; ++r)
                Out[(size_t)(rowb + r) * N_DIM + col] = v[r] + bv;
        }
    }
}

extern "C" void kernel_launch(void* const* d_in, const int* in_sizes, int n_in,
                              void* d_out, int out_size, void* d_ws, size_t ws_size,
                              hipStream_t stream) {
    const float* X    = (const float*)d_in[0];  // [8192][4096]
    const float* W    = (const float*)d_in[1];  // [4096][4096]
    const float* Bias = (const float*)d_in[2];  // [4096]
    float* Out = (float*)d_out;

    const size_t nX = (size_t)M_DIM * K_DIM;          // 33554432
    const size_t nW = (size_t)N_DIM * K_DIM;          // 16777216
    const size_t need = (nX + nW) * sizeof(unsigned short);  // ~96 MB

    if (ws_size >= need) {
        unsigned short* wsX = (unsigned short*)d_ws;
        unsigned short* wsW = wsX + nX;
        const int nX8   = (int)(nX / 8);
        const int nTot8 = (int)((nX + nW) / 8);
        cvt_f32_to_bf16_2<<<2048, 256, 0, stream>>>(X, W, wsX, wsW, nX8, nTot8);
        gemm_256_pipe<<<dim3(512), dim3(512), 0, stream>>>(wsX, wsW, Bias, Out);
    } else {
        dim3 grid(M_DIM / 128, N_DIM / 128);
        gemm_bt_reg<<<grid, dim3(256), 0, stream>>>(X, W, Bias, Out);
    }
}